// Round 5
// baseline (1448.035 us; speedup 1.0000x reference)
//
#include <hip/hip_runtime.h>

typedef __attribute__((ext_vector_type(8))) __bf16 bf16x8;
typedef __attribute__((ext_vector_type(4))) __bf16 bf16x4;
typedef __attribute__((ext_vector_type(4))) float f32x4;
typedef __attribute__((ext_vector_type(2))) float f32x2;
typedef __attribute__((ext_vector_type(8))) int i32x8;

#define AS1 __attribute__((address_space(1)))
#define AS3 __attribute__((address_space(3)))

__device__ __forceinline__ void ld_g2l16(const void* g, void* l) {
    // 16B/lane direct global->LDS (m97). LDS dest is wave-uniform base.
    __builtin_amdgcn_global_load_lds((AS1 void*)g, (AS3 void*)l, 16, 0, 0);
}

__device__ __forceinline__ unsigned char fp8_of(float v) {
    return (unsigned char)(__builtin_amdgcn_cvt_pk_fp8_f32(v, v, 0, false) & 0xFF);
}

// ---------------------------------------------------------------------------
// fp8 GEMM: acc = sum_k A[m,k]*B[n,k]  (A:[M,K], B:[N,K] fp8-e4m3)
// 128x128 tile, BK=128, 4 waves 2x2, 4x4 of 16x16x128 scaled-MFMA (unit E8M0).
// MODE 0: Cb8[m,n] = fp8(acc*oscale + bias[n]*bscale)      (LDS byte repack)
// MODE 1: xv = Cf + acc*oscale + bias[n]; Cf = xv (fp32); Cb8 = fp8(xv)
// ---------------------------------------------------------------------------
template<int MODE>
__global__ void gemm_fp8(const unsigned char* __restrict__ A,
                         const unsigned char* __restrict__ B,
                         const float* __restrict__ bias,
                         unsigned char* __restrict__ Cb8, float* __restrict__ Cf,
                         int M, int N, int K, float oscale, float bscale)
{
    __shared__ __align__(32) unsigned char smem[34816]; // As 16K + Bs 16K; epi 128x144 fp8
    unsigned char* As = smem;
    unsigned char* Bs = smem + 16384;
    const int tid = threadIdx.x;
    const int wave = tid >> 6, lane = tid & 63;
    const int quad = lane >> 4, l15 = lane & 15;
    const int lrow = lane >> 3, lcol = lane & 7;
    const int m0 = blockIdx.y * 128, n0 = blockIdx.x * 128;
    const int wm = wave & 1, wn = wave >> 1;
    const unsigned char* Ab = A + (size_t)m0 * K;
    const unsigned char* Bb = B + (size_t)n0 * K;

    f32x4 acc[4][4] = {};

    for (int k0 = 0; k0 < K; k0 += 128) {
        __syncthreads();
        #pragma unroll
        for (int j = 0; j < 4; ++j) {
            const int chunk = wave * 4 + j;          // 16 chunks of 8 rows (128B each)
            const int row = chunk * 8 + lrow;
            ld_g2l16(Ab + (size_t)row * K + k0 + lcol * 16, &As[chunk * 1024]);
            ld_g2l16(Bb + (size_t)row * K + k0 + lcol * 16, &Bs[chunk * 1024]);
        }
        __syncthreads();
        i32x8 af[4], bfr[4];
        #pragma unroll
        for (int r = 0; r < 4; ++r)
            af[r] = *(const i32x8*)&As[(wm * 64 + r * 16 + l15) * 128 + quad * 32];
        #pragma unroll
        for (int c = 0; c < 4; ++c)
            bfr[c] = *(const i32x8*)&Bs[(wn * 64 + c * 16 + l15) * 128 + quad * 32];
        #pragma unroll
        for (int r = 0; r < 4; ++r)
            #pragma unroll
            for (int c = 0; c < 4; ++c)
                acc[r][c] = __builtin_amdgcn_mfma_scale_f32_16x16x128_f8f6f4(
                    af[r], bfr[c], acc[r][c], 0, 0, 0, 0x7F7F7F7F, 0, 0x7F7F7F7F);
    }

    // C/D layout (measured, shape-determined): col = lane&15, row = quad*4 + reg
    if (MODE == 0) {
        __syncthreads();
        unsigned char (*Cs)[144] = (unsigned char(*)[144])smem;
        #pragma unroll
        for (int r = 0; r < 4; ++r)
            #pragma unroll
            for (int c = 0; c < 4; ++c) {
                const float bv = bias[n0 + wn * 64 + c * 16 + l15] * bscale;
                #pragma unroll
                for (int e = 0; e < 4; ++e)
                    Cs[wm * 64 + r * 16 + quad * 4 + e][wn * 64 + c * 16 + l15] =
                        fp8_of(acc[r][c][e] * oscale + bv);
            }
        __syncthreads();
        #pragma unroll
        for (int p = 0; p < 4; ++p) {
            const int i = p * 256 + tid;      // 1024 chunks of 16B (128 rows x 8)
            const int row = i >> 3, ch = i & 7;
            *(uint4*)&Cb8[(size_t)(m0 + row) * N + n0 + ch * 16] =
                *(const uint4*)&Cs[row][ch * 16];
        }
    } else {
        #pragma unroll
        for (int r = 0; r < 4; ++r)
            #pragma unroll
            for (int c = 0; c < 4; ++c)
                #pragma unroll
                for (int e = 0; e < 4; ++e) {
                    const int m = m0 + wm * 64 + r * 16 + quad * 4 + e;
                    const int n = n0 + wn * 64 + c * 16 + l15;
                    const float v = acc[r][c][e] * oscale + bias[n];
                    const size_t idx = (size_t)m * N + n;
                    const float xv = Cf[idx] + v;
                    Cf[idx] = xv;
                    Cb8[idx] = fp8_of(xv);
                }
    }
}

// ---------------------------------------------------------------------------
// s_partial: P[ch][bh][d2][d1] = sum_{t in chunk} K[t,d1]*V[t,d2]
// qkv8 layout [b,t,3072] fp8 (scale 2^7): Q at 0, K at +1024, V at +2048.
// fp8->bf16 conversion in LDS staging; the 2^14 product scale is folded into
// s_reduce's constant. Output [d2][d1] to match y_kernel's B-fragment reads.
// ---------------------------------------------------------------------------
__global__ void s_partial(const unsigned char* __restrict__ qkv8, float* __restrict__ P)
{
    constexpr int CH = 128;
    __shared__ __align__(16) __bf16 Kt[64][CH + 8];
    __shared__ __align__(16) __bf16 Vt[64][CH + 8];
    const int bh = blockIdx.x, chb = blockIdx.y;
    const int b = bh >> 4, h = bh & 15;
    const int t0 = chb * CH;
    const int tid = threadIdx.x;
    const int wave = tid >> 6, lane = tid & 63;
    const int quad = lane >> 4, l15 = lane & 15;
    const unsigned char* Kb8 = qkv8 + (size_t)b * 2048 * 3072 + 1024 + h * 64;
    const unsigned char* Vb8 = Kb8 + 1024;

    for (int i = tid; i < CH * 16; i += 256) {
        const int t = i >> 4, d4 = (i & 15) * 4;
        const unsigned int kw = *(const unsigned int*)(Kb8 + (size_t)(t0 + t) * 3072 + d4);
        const unsigned int vw = *(const unsigned int*)(Vb8 + (size_t)(t0 + t) * 3072 + d4);
        const f32x2 a0 = __builtin_amdgcn_cvt_pk_f32_fp8(kw, false);
        const f32x2 a1 = __builtin_amdgcn_cvt_pk_f32_fp8(kw, true);
        const f32x2 b0 = __builtin_amdgcn_cvt_pk_f32_fp8(vw, false);
        const f32x2 b1 = __builtin_amdgcn_cvt_pk_f32_fp8(vw, true);
        Kt[d4 + 0][t] = (__bf16)a0[0];  Kt[d4 + 1][t] = (__bf16)a0[1];
        Kt[d4 + 2][t] = (__bf16)a1[0];  Kt[d4 + 3][t] = (__bf16)a1[1];
        Vt[d4 + 0][t] = (__bf16)b0[0];  Vt[d4 + 1][t] = (__bf16)b0[1];
        Vt[d4 + 2][t] = (__bf16)b1[0];  Vt[d4 + 3][t] = (__bf16)b1[1];
    }
    __syncthreads();

    f32x4 acc[4] = {};
    #pragma unroll
    for (int s = 0; s < CH / 32; ++s) {
        const bf16x8 a = *(const bf16x8*)&Kt[wave * 16 + l15][s * 32 + quad * 8];  // m=d1
        #pragma unroll
        for (int c = 0; c < 4; ++c) {
            const bf16x8 bb = *(const bf16x8*)&Vt[c * 16 + l15][s * 32 + quad * 8]; // n=d2
            acc[c] = __builtin_amdgcn_mfma_f32_16x16x32_bf16(a, bb, acc[c], 0, 0, 0);
        }
    }

    // store as [d2][d1]: row = d2 = c*16+l15, col = d1 = wave*16+quad*4+e
    float* Pb = P + ((size_t)chb * 64 + bh) * 4096;
    #pragma unroll
    for (int c = 0; c < 4; ++c)
        *(f32x4*)&Pb[(size_t)(c * 16 + l15) * 64 + wave * 16 + quad * 4] = acc[c];
}

// s_reduce: St[bh][d2][d1] = 2^-17 * sum_ch P  (0.125 attn scale x 2^-14 fp8 scales)
__global__ void s_reduce(const float* __restrict__ P, __bf16* __restrict__ St)
{
    const int g = blockIdx.x * 256 + threadIdx.x;   // vec4 index, 65536 total
    f32x4 s = {};
    #pragma unroll
    for (int ch = 0; ch < 16; ++ch)
        s += *(const f32x4*)&P[(size_t)ch * 262144 + (size_t)g * 4];
    bf16x4 o;
    #pragma unroll
    for (int e = 0; e < 4; ++e) o[e] = (__bf16)(s[e] * 7.62939453125e-06f);
    *(bf16x4*)&St[(size_t)g * 4] = o;
}

// ---------------------------------------------------------------------------
// Y kernel: Y8[b,t,h*64+d2] = fp8( 2^14 * sum_d1 Q[t,d1] * St[bh][d2][d1] )
// Q read as fp8 (scale 2^7), converted in staging; epilogue x 2^7 = 2^14*2^-7.
// ---------------------------------------------------------------------------
__global__ void y_kernel(const unsigned char* __restrict__ qkv8,
                         const __bf16* __restrict__ St,
                         unsigned char* __restrict__ Y)
{
    __shared__ __align__(16) unsigned char smem[32768];  // Qs 256x64 bf16; epi 256x72 fp8
    __bf16* Qs = (__bf16*)smem;
    const int bh = blockIdx.y, b = bh >> 4, h = bh & 15;
    const int t0 = blockIdx.x * 256;
    const int tid = threadIdx.x;
    const int wave = tid >> 6, lane = tid & 63;
    const int quad = lane >> 4, l15 = lane & 15;
    const unsigned char* Qb8 = qkv8 + ((size_t)b * 2048 + t0) * 3072 + h * 64;

    #pragma unroll
    for (int p = 0; p < 4; ++p) {
        const int idx = p * 256 + tid;               // 1024 = 256 rows x 4 segs
        const int row = idx >> 2, seg = idx & 3;
        const uint4 w = *(const uint4*)(Qb8 + (size_t)row * 3072 + seg * 16);
        const unsigned int ws[4] = { w.x, w.y, w.z, w.w };
        bf16x8 v0, v1;
        #pragma unroll
        for (int j = 0; j < 2; ++j) {
            const f32x2 lo = __builtin_amdgcn_cvt_pk_f32_fp8(ws[j], false);
            const f32x2 hi = __builtin_amdgcn_cvt_pk_f32_fp8(ws[j], true);
            v0[j * 4 + 0] = (__bf16)lo[0];  v0[j * 4 + 1] = (__bf16)lo[1];
            v0[j * 4 + 2] = (__bf16)hi[0];  v0[j * 4 + 3] = (__bf16)hi[1];
        }
        #pragma unroll
        for (int j = 0; j < 2; ++j) {
            const f32x2 lo = __builtin_amdgcn_cvt_pk_f32_fp8(ws[2 + j], false);
            const f32x2 hi = __builtin_amdgcn_cvt_pk_f32_fp8(ws[2 + j], true);
            v1[j * 4 + 0] = (__bf16)lo[0];  v1[j * 4 + 1] = (__bf16)lo[1];
            v1[j * 4 + 2] = (__bf16)hi[0];  v1[j * 4 + 3] = (__bf16)hi[1];
        }
        *(bf16x8*)&Qs[row * 64 + seg * 16] = v0;
        *(bf16x8*)&Qs[row * 64 + seg * 16 + 8] = v1;
    }

    f32x4 acc[4][4] = {};
    const __bf16* Sb = St + (size_t)bh * 4096;
    __syncthreads();
    #pragma unroll
    for (int s = 0; s < 2; ++s) {
        bf16x8 af[4], bfr[4];
        #pragma unroll
        for (int r = 0; r < 4; ++r)
            af[r] = *(const bf16x8*)&Qs[(wave * 64 + r * 16 + l15) * 64 + s * 32 + quad * 8];
        #pragma unroll
        for (int c = 0; c < 4; ++c)
            bfr[c] = *(const bf16x8*)&Sb[(size_t)(c * 16 + l15) * 64 + s * 32 + quad * 8];
        #pragma unroll
        for (int r = 0; r < 4; ++r)
            #pragma unroll
            for (int c = 0; c < 4; ++c)
                acc[r][c] = __builtin_amdgcn_mfma_f32_16x16x32_bf16(af[r], bfr[c], acc[r][c], 0, 0, 0);
    }

    __syncthreads();
    unsigned char (*Cs)[72] = (unsigned char(*)[72])smem;
    #pragma unroll
    for (int r = 0; r < 4; ++r)
        #pragma unroll
        for (int c = 0; c < 4; ++c)
            #pragma unroll
            for (int e = 0; e < 4; ++e)
                Cs[wave * 64 + r * 16 + quad * 4 + e][c * 16 + l15] =
                    fp8_of(acc[r][c][e] * 128.0f);
    __syncthreads();
    #pragma unroll
    for (int p = 0; p < 4; ++p) {
        const int i = p * 256 + tid;                 // 1024 chunks of 16B
        const int row = i >> 2, ch = i & 3;
        *(uint4*)&Y[((size_t)b * 2048 + t0 + row) * 1024 + h * 64 + ch * 16] =
            *(const uint4*)&Cs[row][ch * 16];
    }
}

// ---------------------------------------------------------------------------
__global__ void cvt_fp8(const float* __restrict__ src, unsigned int* __restrict__ dst,
                        float scale, int n4)
{
    const int i = blockIdx.x * 256 + threadIdx.x;
    if (i >= n4) return;
    const float4 v = ((const float4*)src)[i];
    int w = __builtin_amdgcn_cvt_pk_fp8_f32(v.x * scale, v.y * scale, 0, false);
    w = __builtin_amdgcn_cvt_pk_fp8_f32(v.z * scale, v.w * scale, w, true);
    dst[i] = (unsigned int)w;
}

__global__ void init_x(const float* __restrict__ src, unsigned int* __restrict__ x8,
                       float* __restrict__ xF, int n4)
{
    const int i = blockIdx.x * 256 + threadIdx.x;
    if (i >= n4) return;
    const float4 v = ((const float4*)src)[i];
    ((float4*)xF)[i] = v;
    int w = __builtin_amdgcn_cvt_pk_fp8_f32(v.x, v.y, 0, false);
    w = __builtin_amdgcn_cvt_pk_fp8_f32(v.z, v.w, w, true);
    x8[i] = (unsigned int)w;
}

// ---------------------------------------------------------------------------
extern "C" void kernel_launch(void* const* d_in, const int* in_sizes, int n_in,
                              void* d_out, int out_size, void* d_ws, size_t ws_size,
                              hipStream_t stream)
{
    const float* x0    = (const float*)d_in[0];   // [4,2048,1024]
    const float* Wqkv  = (const float*)d_in[1];   // [12,3072,1024]
    const float* bqkv  = (const float*)d_in[2];   // [12,3072]
    const float* Wproj = (const float*)d_in[3];   // [12,1024,1024]
    const float* bproj = (const float*)d_in[4];   // [12,1024]
    float* xF = (float*)d_out;                    // fp32 x master lives in d_out

    char* p = (char*)d_ws;
    unsigned char* WqkvF8  = (unsigned char*)p; p += (size_t)12 * 3072 * 1024;  // 37.7 MB
    unsigned char* WprojF8 = (unsigned char*)p; p += (size_t)12 * 1024 * 1024;  // 12.6 MB
    unsigned char* xB      = (unsigned char*)p; p += (size_t)8192 * 1024;       //  8.4 MB
    unsigned char* qkv8    = (unsigned char*)p; p += (size_t)8192 * 3072;       // 25.2 MB
    float*  P  = (float*)p;  p += (size_t)16 * 64 * 4096 * 4;                   // 16.8 MB
    __bf16* St = (__bf16*)p; p += (size_t)64 * 4096 * 2;                        //  0.5 MB
    unsigned char* Y = (unsigned char*)p; p += (size_t)8192 * 1024;             //  8.4 MB

    const float SW = 4096.0f;             // weight fp8 scale 2^12
    // qkv epilogue: (acc*2^-12 + bias) * 2^7  -> oscale 2^-5, bscale 2^7
    const float OS0 = 1.0f / 32.0f, BS0 = 128.0f;
    const float D1 = 1.0f / 67108864.0f;  // proj descale: Y(2^14) * W(2^12) = 2^-26

    cvt_fp8<<<36864, 256, 0, stream>>>(Wqkv, (unsigned int*)WqkvF8, SW, 9437184);
    cvt_fp8<<<12288, 256, 0, stream>>>(Wproj, (unsigned int*)WprojF8, SW, 3145728);
    init_x<<<8192, 256, 0, stream>>>(x0, (unsigned int*)xB, xF, 2097152);

    for (int i = 0; i < 12; ++i) {
        // qkv8 = fp8( (x @ Wqkv^T + bqkv) * 2^7 )      [8192,3072]
        gemm_fp8<0><<<dim3(24, 64), 256, 0, stream>>>(
            xB, WqkvF8 + (size_t)i * 3145728, bqkv + i * 3072,
            qkv8, nullptr, 8192, 3072, 1024, OS0, BS0);
        // St[bh][d2][d1] = scale * K^T V  (fp8 scales folded into s_reduce)
        s_partial<<<dim3(64, 16), 256, 0, stream>>>(qkv8, P);
        s_reduce<<<256, 256, 0, stream>>>(P, St);
        // Y8 = fp8( 2^14 * Q @ S )                     [8192,1024]
        y_kernel<<<dim3(8, 64), 256, 0, stream>>>(qkv8, St, Y);
        // x = x + Y @ Wproj^T + bproj  (fp32 master + fp8 copy)
        gemm_fp8<1><<<dim3(8, 64), 256, 0, stream>>>(
            Y, WprojF8 + (size_t)i * 1048576, bproj + i * 1024,
            xB, xF, 8192, 1024, 1024, D1, 1.0f);
    }
}